// Round 3
// baseline (861.965 us; speedup 1.0000x reference)
//
#include <hip/hip_runtime.h>
#include <hip/hip_bf16.h>

#define N_NODES 100000
#define N_EDGES 3200000
#define D 64
#define NEG_SLOPE 0.01f

#define B_SHIFT 9                          // bucket = 512 nodes
#define NB ((N_NODES + 511) >> B_SHIFT)    // 196 buckets
#define T_EDGES 4096                       // edges per binning block
#define NBIN ((N_EDGES + T_EDGES - 1) / T_EDGES)  // 782 binning blocks

#define NG 25000                           // node-blocks per feature-quarter phase
#define QROW 16                            // cols per quarter

__device__ __forceinline__ unsigned short f2bf(float f) {
    __hip_bfloat16 h = __float2bfloat16(f);
    return *reinterpret_cast<unsigned short*>(&h);
}
__device__ __forceinline__ float bflo(unsigned int u) { return __uint_as_float(u << 16); }
__device__ __forceinline__ float bfhi(unsigned int u) { return __uint_as_float(u & 0xffff0000u); }

// ---------------- bucket histogram (196 counters, LDS-accumulated) ----------------
__global__ __launch_bounds__(256) void bhist_k(const int* __restrict__ dst, int* __restrict__ btot) {
    __shared__ int hist[NB];
    int tid = threadIdx.x;
    for (int b = tid; b < NB; b += 256) hist[b] = 0;
    __syncthreads();
    int e0 = blockIdx.x * T_EDGES;
    int e1 = min(e0 + T_EDGES, N_EDGES);
    for (int e = e0 + tid; e < e1; e += 256) atomicAdd(&hist[dst[e] >> B_SHIFT], 1);
    __syncthreads();
    for (int b = tid; b < NB; b += 256) {
        int h = hist[b];
        if (h) atomicAdd(&btot[b], h);
    }
}

// one-block exclusive scan over the 196 bucket totals -> bbase[0..NB]
__global__ __launch_bounds__(256) void bscan_k(const int* __restrict__ btot, int* __restrict__ bbase) {
    __shared__ int wsum[4];
    int t = threadIdx.x;
    int lane = t & 63, w = t >> 6;
    int v = (t < NB) ? btot[t] : 0;
    int incl = v;
    #pragma unroll
    for (int o = 1; o < 64; o <<= 1) {
        int u = __shfl_up(incl, o, 64);
        if (lane >= o) incl += u;
    }
    if (lane == 63) wsum[w] = incl;
    __syncthreads();
    int woff = 0;
    for (int k = 0; k < w; ++k) woff += wsum[k];
    if (t < NB) bbase[t] = woff + incl - v;
    if (t == NB) bbase[NB] = N_EDGES;
}

// ---------------- coarse placement: LDS-reorder then coalesced stream-out ----------------
__global__ __launch_bounds__(256) void bucket_k(const int* __restrict__ src, const int* __restrict__ dst,
                                                const int* __restrict__ bbase, int* __restrict__ bcnt2,
                                                int2* __restrict__ pairs) {
    __shared__ int hist[NB];
    __shared__ int lbase[NB];
    __shared__ int lcnt[NB];
    __shared__ int gbase[NB];   // global run base with -lbase folded in
    __shared__ int wsum[4];
    __shared__ int2 buf[T_EDGES];   // 32 KB reorder buffer
    int tid = threadIdx.x;
    for (int b = tid; b < NB; b += 256) { hist[b] = 0; lcnt[b] = 0; }
    __syncthreads();
    int e0 = blockIdx.x * T_EDGES;
    int e1 = min(e0 + T_EDGES, N_EDGES);
    for (int e = e0 + tid; e < e1; e += 256) atomicAdd(&hist[dst[e] >> B_SHIFT], 1);
    __syncthreads();
    {
        int v = (tid < NB) ? hist[tid] : 0;
        int lane = tid & 63, w = tid >> 6;
        int incl = v;
        #pragma unroll
        for (int o = 1; o < 64; o <<= 1) {
            int u = __shfl_up(incl, o, 64);
            if (lane >= o) incl += u;
        }
        if (lane == 63) wsum[w] = incl;
        __syncthreads();
        int woff = 0;
        for (int k = 0; k < w; ++k) woff += wsum[k];
        if (tid < NB) {
            int excl = woff + incl - v;
            lbase[tid] = excl;
            int p = v ? atomicAdd(&bcnt2[tid], v) : 0;
            gbase[tid] = bbase[tid] + p - excl;   // so stream-out addr = gbase[b] + i
        }
    }
    __syncthreads();
    for (int e = e0 + tid; e < e1; e += 256) {
        int sv = src[e], dv = dst[e];
        int b = dv >> B_SHIFT;
        int loc = lbase[b] + atomicAdd(&lcnt[b], 1);
        buf[loc] = make_int2(sv, dv);
    }
    __syncthreads();
    int n = e1 - e0;
    for (int i = tid; i < n; i += 256) {
        int2 pr = buf[i];
        int b = pr.y >> B_SHIFT;
        pairs[gbase[b] + i] = pr;
    }
}

// ---------------- fine: per-bucket degree count + scan + scatter ----------------
__global__ __launch_bounds__(512) void fine_k(const int2* __restrict__ pairs, const int* __restrict__ bbase,
                                              int* __restrict__ degi, int* __restrict__ offs,
                                              float* __restrict__ rsd, int* __restrict__ csr_src) {
    __shared__ int cnt[512];
    __shared__ int offl[512];
    __shared__ int wsum[8];
    int b = blockIdx.x, t = threadIdx.x;
    int start = bbase[b];
    int end = bbase[b + 1];
    cnt[t] = 0;
    __syncthreads();
    for (int e = start + t; e < end; e += 512) atomicAdd(&cnt[pairs[e].y & 511], 1);
    __syncthreads();
    int d = cnt[t];
    int lane = t & 63, w = t >> 6;
    int incl = d;
    #pragma unroll
    for (int o = 1; o < 64; o <<= 1) {
        int u = __shfl_up(incl, o, 64);
        if (lane >= o) incl += u;
    }
    if (lane == 63) wsum[w] = incl;
    __syncthreads();
    int woff = 0;
    for (int k = 0; k < w; ++k) woff += wsum[k];
    int myoff = start + woff + incl - d;
    offl[t] = myoff;
    int n = (b << B_SHIFT) + t;
    if (n < N_NODES) {
        degi[n] = d;
        offs[n] = myoff;
        rsd[n] = rsqrtf((float)(d > 0 ? d : 1));
    }
    cnt[t] = 0;
    __syncthreads();
    for (int e = start + t; e < end; e += 512) {
        int2 pr = pairs[e];
        int li = pr.y & 511;
        int p = atomicAdd(&cnt[li], 1);
        csr_src[offl[li] + p] = pr.x;
    }
}

// ---------------- convert x -> rsd-prescaled bf16, QUARTERED column-block tables ----
// table f (f=0..3) holds cols [16f,16f+16) for all nodes: [N][16] bf16 = 3.2 MB.
__global__ __launch_bounds__(256) void cvt_k(const float* __restrict__ x, const float* __restrict__ rsd,
                                             unsigned short* __restrict__ xq) {
    int i = blockIdx.x * 256 + threadIdx.x;     // one float4 (4 cols)
    if (i < N_NODES * 16) {
        int node = i >> 4;
        int q = i & 15;                 // col-group 4q..4q+3
        int f = q >> 2;                 // quarter table
        float rn = rsd[node];
        float4 v = ((const float4*)x)[i];
        unsigned int lo = ((unsigned int)f2bf(rn * v.y) << 16) | f2bf(rn * v.x);
        unsigned int hi = ((unsigned int)f2bf(rn * v.w) << 16) | f2bf(rn * v.z);
        uint2* tab = (uint2*)(xq + (size_t)f * N_NODES * QROW);
        tab[node * 4 + (q & 3)] = make_uint2(lo, hi);
    }
}

// ---------------- per-layer: neighbor sum, one feature-quarter per macro-phase ----
// grid = 4*NG blocks; f = blockIdx/NG selects the 3.2 MB quarter table (fits 4 MiB
// per-XCD L2; dispatch-order phasing keeps all resident blocks on the same table).
// wave per node: lane = (edge-slot g 0..31, half-row h 0..1), uint4 = 8 bf16/lane.
__global__ __launch_bounds__(256) void agq_k(const unsigned short* __restrict__ xq,
                                             const float* __restrict__ rsd,
                                             const int* __restrict__ offs, const int* __restrict__ degi,
                                             const int* __restrict__ csr_src, float* __restrict__ s) {
    int f = blockIdx.x / NG;
    int bg = blockIdx.x - f * NG;
    int node = bg * 4 + (threadIdx.x >> 6);
    if (node >= N_NODES) return;
    int lane = threadIdx.x & 63;
    int g = lane >> 1;          // edge slot 0..31
    int h = lane & 1;           // half of quarter-row (8 bf16)
    int start = offs[node];
    int deg = degi[node];
    const uint4* tab = (const uint4*)(xq + (size_t)f * N_NODES * QROW);
    float acc0 = 0.f, acc1 = 0.f, acc2 = 0.f, acc3 = 0.f;
    float acc4 = 0.f, acc5 = 0.f, acc6 = 0.f, acc7 = 0.f;
    for (int j = 0; j < deg; j += 32) {
        int e = j + g;
        bool v = e < deg;
        int sj = csr_src[start + (v ? e : 0)];
        float wv = v ? 1.f : 0.f;
        uint4 pk = tab[sj * 2 + h];
        acc0 += wv * bflo(pk.x); acc1 += wv * bfhi(pk.x);
        acc2 += wv * bflo(pk.y); acc3 += wv * bfhi(pk.y);
        acc4 += wv * bflo(pk.z); acc5 += wv * bfhi(pk.z);
        acc6 += wv * bflo(pk.w); acc7 += wv * bfhi(pk.w);
    }
    #pragma unroll
    for (int off = 2; off < 64; off <<= 1) {
        acc0 += __shfl_xor(acc0, off, 64); acc1 += __shfl_xor(acc1, off, 64);
        acc2 += __shfl_xor(acc2, off, 64); acc3 += __shfl_xor(acc3, off, 64);
        acc4 += __shfl_xor(acc4, off, 64); acc5 += __shfl_xor(acc5, off, 64);
        acc6 += __shfl_xor(acc6, off, 64); acc7 += __shfl_xor(acc7, off, 64);
    }
    if (g == 0) {   // lanes h=0 (cols 0-7 of quarter) and h=1 (cols 8-15)
        float rn = rsd[node];
        float4 r0, r1;
        r0.x = rn * acc0; r0.y = rn * acc1; r0.z = rn * acc2; r0.w = rn * acc3;
        r1.x = rn * acc4; r1.y = rn * acc5; r1.z = rn * acc6; r1.w = rn * acc7;
        float4* sp = (float4*)s + node * 16 + f * 4 + h * 2;
        sp[0] = r0;
        sp[1] = r1;
    }
}

// ---------------- per-layer: combine + GEMM (round-1 proven core) ----------------
// out[n, d] = act( (in[n]+s[n]) @ W1 + (s[n]*in[n]) @ W2 ); bf16 epilogue writes
// hq[f][n] = rsd[n]*h[n] quartered tables for the next layer's aggregation.
__global__ __launch_bounds__(256) void comb_k(const float* __restrict__ in, int stride,
                                              const float* __restrict__ s,
                                              const float* __restrict__ W1, const float* __restrict__ W2,
                                              float* __restrict__ out, int act,
                                              unsigned short* __restrict__ hq, const float* __restrict__ rsd,
                                              int bfout) {
    __shared__ float W1s[D * D];
    __shared__ float W2s[D * D];
    __shared__ float aL[4][4][D];   // [wave][m][k]
    __shared__ float bL[4][4][D];
    int tid = threadIdx.x;
    {
        const float4* w1v = (const float4*)W1;
        const float4* w2v = (const float4*)W2;
        float4* w1s = (float4*)W1s;
        float4* w2s = (float4*)W2s;
        for (int t = tid; t < D * D / 4; t += 256) { w1s[t] = w1v[t]; w2s[t] = w2v[t]; }
    }
    int w = tid >> 6;
    int l = tid & 63;
    int m = l >> 4;
    int cb = (l & 15) * 4;
    __syncthreads();
    for (int it = 0; it < 2; ++it) {
        int n0 = blockIdx.x * 32 + it * 16 + w * 4;
        #pragma unroll
        for (int mm = 0; mm < 4; ++mm) {
            float xv = in[(size_t)(n0 + mm) * stride + l];
            float sp = s[(size_t)(n0 + mm) * D + l];
            aL[w][mm][l] = xv + sp;
            bL[w][mm][l] = sp * xv;
        }
        __syncthreads();
        float acc0 = 0.f, acc1 = 0.f, acc2 = 0.f, acc3 = 0.f;
        const float4* aV = (const float4*)&aL[w][m][0];
        const float4* bV = (const float4*)&bL[w][m][0];
        #pragma unroll
        for (int kk = 0; kk < 16; ++kk) {
            float4 a4 = aV[kk];
            float4 b4 = bV[kk];
            #pragma unroll
            for (int j = 0; j < 4; ++j) {
                int k = kk * 4 + j;
                float aj = (j == 0) ? a4.x : (j == 1) ? a4.y : (j == 2) ? a4.z : a4.w;
                float bj = (j == 0) ? b4.x : (j == 1) ? b4.y : (j == 2) ? b4.z : b4.w;
                float4 w1 = *(const float4*)&W1s[k * D + cb];
                float4 w2 = *(const float4*)&W2s[k * D + cb];
                acc0 += aj * w1.x + bj * w2.x;
                acc1 += aj * w1.y + bj * w2.y;
                acc2 += aj * w1.z + bj * w2.z;
                acc3 += aj * w1.w + bj * w2.w;
            }
        }
        int n = n0 + m;
        float4 r;
        r.x = acc0; r.y = acc1; r.z = acc2; r.w = acc3;
        if (act) {
            r.x = r.x >= 0.f ? r.x : NEG_SLOPE * r.x;
            r.y = r.y >= 0.f ? r.y : NEG_SLOPE * r.y;
            r.z = r.z >= 0.f ? r.z : NEG_SLOPE * r.z;
            r.w = r.w >= 0.f ? r.w : NEG_SLOPE * r.w;
        }
        *(float4*)&out[(size_t)n * 192 + cb] = r;
        if (bfout) {
            float rn = rsd[n];
            unsigned int lo = ((unsigned int)f2bf(rn * r.y) << 16) | f2bf(rn * r.x);
            unsigned int hi = ((unsigned int)f2bf(rn * r.w) << 16) | f2bf(rn * r.z);
            int fq = cb >> 4;   // quarter table
            uint2* tab = (uint2*)(hq + (size_t)fq * N_NODES * QROW);
            tab[n * 4 + ((cb & 15) >> 2)] = make_uint2(lo, hi);
        }
        __syncthreads();
    }
}

extern "C" void kernel_launch(void* const* d_in, const int* in_sizes, int n_in,
                              void* d_out, int out_size, void* d_ws, size_t ws_size,
                              hipStream_t stream) {
    const float* x   = (const float*)d_in[0];
    const float* W1a = (const float*)d_in[1];
    const float* W2a = (const float*)d_in[2];
    const float* W1b = (const float*)d_in[3];
    const float* W2b = (const float*)d_in[4];
    const int*   src = (const int*)d_in[5];
    const int*   dst = (const int*)d_in[6];
    float* out = (float*)d_out;

    // workspace layout (~65 MB); xq/hq ALIAS pairs (pairs is dead after fine_k)
    int*   btot    = (int*)d_ws;                    // NB pad 256
    int*   bcnt2   = btot + 256;                    // NB pad 256
    int*   bbase   = bcnt2 + 256;                   // NB+1 pad 256
    int*   degi    = bbase + 256;                   // N
    int*   offs    = degi + N_NODES;                // N
    float* rsd     = (float*)(offs + N_NODES);      // N
    int*   csr_src = (int*)(rsd + N_NODES);         // E
    int2*  pairs   = (int2*)(csr_src + N_EDGES);    // E (25.6 MB)
    unsigned short* xq = (unsigned short*)pairs;        // 4 quarter-tables (12.8 MB)
    unsigned short* hq = xq + (size_t)N_NODES * D;      // 4 quarter-tables (12.8 MB)
    float* s       = (float*)(pairs + N_EDGES);     // N*D

    hipMemsetAsync(btot, 0, 512 * sizeof(int), stream);  // btot + bcnt2

    bhist_k<<<NBIN, 256, 0, stream>>>(dst, btot);
    bscan_k<<<1, 256, 0, stream>>>(btot, bbase);
    bucket_k<<<NBIN, 256, 0, stream>>>(src, dst, bbase, bcnt2, pairs);
    fine_k<<<NB, 512, 0, stream>>>(pairs, bbase, degi, offs, rsd, csr_src);
    cvt_k<<<(N_NODES * 16 + 255) / 256, 256, 0, stream>>>(x, rsd, xq);   // pairs dead, rsd ready

    int ag = 4 * NG;              // 4 feature-quarter phases x 25000 node-blocks
    int cbg = N_NODES / 32;       // 3125, exact

    // layer 1: h1 = lrelu(conv(x, W1a, W2a)) -> out cols [0,64), hq = rsd*h1 (bf16)
    agq_k<<<ag, 256, 0, stream>>>(xq, rsd, offs, degi, csr_src, s);
    comb_k<<<cbg, 256, 0, stream>>>(x, D, s, W1a, W2a, out + 0, 1, hq, rsd, 1);
    // layer 2: h2 = lrelu(conv(h1, W1b, W2b)) -> out cols [64,128), hq = rsd*h2 (bf16)
    agq_k<<<ag, 256, 0, stream>>>(hq, rsd, offs, degi, csr_src, s);
    comb_k<<<cbg, 256, 0, stream>>>(out + 0, 192, s, W1b, W2b, out + 64, 1, hq, rsd, 1);
    // layer 3: h3 = conv(h2, W1b, W2b) (no act) -> out cols [128,192)
    agq_k<<<ag, 256, 0, stream>>>(hq, rsd, offs, degi, csr_src, s);
    comb_k<<<cbg, 256, 0, stream>>>(out + 64, 192, s, W1b, W2b, out + 128, 0, hq, rsd, 0);
}

// Round 4
// 534.097 us; speedup vs baseline: 1.6139x; 1.6139x over previous
//
#include <hip/hip_runtime.h>
#include <hip/hip_bf16.h>

#define N_NODES 100000
#define N_EDGES 3200000
#define D 64
#define NEG_SLOPE 0.01f

#define B_SHIFT 9                          // bucket = 512 nodes
#define NB ((N_NODES + 511) >> B_SHIFT)    // 196 buckets
#define T_EDGES 4096                       // edges per binning block
#define NBIN ((N_EDGES + T_EDGES - 1) / T_EDGES)  // 782 binning blocks

__device__ __forceinline__ unsigned short f2bf(float f) {
    __hip_bfloat16 h = __float2bfloat16(f);
    return *reinterpret_cast<unsigned short*>(&h);
}
__device__ __forceinline__ float bflo(unsigned int u) { return __uint_as_float(u << 16); }
__device__ __forceinline__ float bfhi(unsigned int u) { return __uint_as_float(u & 0xffff0000u); }

// ---------------- bucket histogram (196 counters, LDS-accumulated) ----------------
__global__ __launch_bounds__(256) void bhist_k(const int* __restrict__ dst, int* __restrict__ btot) {
    __shared__ int hist[NB];
    int tid = threadIdx.x;
    for (int b = tid; b < NB; b += 256) hist[b] = 0;
    __syncthreads();
    int e0 = blockIdx.x * T_EDGES;
    int e1 = min(e0 + T_EDGES, N_EDGES);
    for (int e = e0 + tid; e < e1; e += 256) atomicAdd(&hist[dst[e] >> B_SHIFT], 1);
    __syncthreads();
    for (int b = tid; b < NB; b += 256) {
        int h = hist[b];
        if (h) atomicAdd(&btot[b], h);
    }
}

// one-block exclusive scan over the 196 bucket totals -> bbase[0..NB]
__global__ __launch_bounds__(256) void bscan_k(const int* __restrict__ btot, int* __restrict__ bbase) {
    __shared__ int wsum[4];
    int t = threadIdx.x;
    int lane = t & 63, w = t >> 6;
    int v = (t < NB) ? btot[t] : 0;
    int incl = v;
    #pragma unroll
    for (int o = 1; o < 64; o <<= 1) {
        int u = __shfl_up(incl, o, 64);
        if (lane >= o) incl += u;
    }
    if (lane == 63) wsum[w] = incl;
    __syncthreads();
    int woff = 0;
    for (int k = 0; k < w; ++k) woff += wsum[k];
    if (t < NB) bbase[t] = woff + incl - v;
    if (t == NB) bbase[NB] = N_EDGES;
}

// ---------------- coarse placement: LDS-reorder then coalesced stream-out ----------------
__global__ __launch_bounds__(256) void bucket_k(const int* __restrict__ src, const int* __restrict__ dst,
                                                const int* __restrict__ bbase, int* __restrict__ bcnt2,
                                                int2* __restrict__ pairs) {
    __shared__ int hist[NB];
    __shared__ int lbase[NB];
    __shared__ int lcnt[NB];
    __shared__ int gbase[NB];   // global run base with -lbase folded in
    __shared__ int wsum[4];
    __shared__ int2 buf[T_EDGES];   // 32 KB reorder buffer
    int tid = threadIdx.x;
    for (int b = tid; b < NB; b += 256) { hist[b] = 0; lcnt[b] = 0; }
    __syncthreads();
    int e0 = blockIdx.x * T_EDGES;
    int e1 = min(e0 + T_EDGES, N_EDGES);
    for (int e = e0 + tid; e < e1; e += 256) atomicAdd(&hist[dst[e] >> B_SHIFT], 1);
    __syncthreads();
    {
        int v = (tid < NB) ? hist[tid] : 0;
        int lane = tid & 63, w = tid >> 6;
        int incl = v;
        #pragma unroll
        for (int o = 1; o < 64; o <<= 1) {
            int u = __shfl_up(incl, o, 64);
            if (lane >= o) incl += u;
        }
        if (lane == 63) wsum[w] = incl;
        __syncthreads();
        int woff = 0;
        for (int k = 0; k < w; ++k) woff += wsum[k];
        if (tid < NB) {
            int excl = woff + incl - v;
            lbase[tid] = excl;
            int p = v ? atomicAdd(&bcnt2[tid], v) : 0;
            gbase[tid] = bbase[tid] + p - excl;   // so stream-out addr = gbase[b] + i
        }
    }
    __syncthreads();
    for (int e = e0 + tid; e < e1; e += 256) {
        int sv = src[e], dv = dst[e];
        int b = dv >> B_SHIFT;
        int loc = lbase[b] + atomicAdd(&lcnt[b], 1);
        buf[loc] = make_int2(sv, dv);
    }
    __syncthreads();
    int n = e1 - e0;
    for (int i = tid; i < n; i += 256) {
        int2 pr = buf[i];
        int b = pr.y >> B_SHIFT;
        pairs[gbase[b] + i] = pr;
    }
}

// ---------------- fine: per-bucket degree count + scan + scatter ----------------
__global__ __launch_bounds__(512) void fine_k(const int2* __restrict__ pairs, const int* __restrict__ bbase,
                                              int* __restrict__ degi, int* __restrict__ offs,
                                              float* __restrict__ rsd, int* __restrict__ csr_src) {
    __shared__ int cnt[512];
    __shared__ int offl[512];
    __shared__ int wsum[8];
    int b = blockIdx.x, t = threadIdx.x;
    int start = bbase[b];
    int end = bbase[b + 1];
    cnt[t] = 0;
    __syncthreads();
    for (int e = start + t; e < end; e += 512) atomicAdd(&cnt[pairs[e].y & 511], 1);
    __syncthreads();
    int d = cnt[t];
    int lane = t & 63, w = t >> 6;
    int incl = d;
    #pragma unroll
    for (int o = 1; o < 64; o <<= 1) {
        int u = __shfl_up(incl, o, 64);
        if (lane >= o) incl += u;
    }
    if (lane == 63) wsum[w] = incl;
    __syncthreads();
    int woff = 0;
    for (int k = 0; k < w; ++k) woff += wsum[k];
    int myoff = start + woff + incl - d;
    offl[t] = myoff;
    int n = (b << B_SHIFT) + t;
    if (n < N_NODES) {
        degi[n] = d;
        offs[n] = myoff;
        rsd[n] = rsqrtf((float)(d > 0 ? d : 1));
    }
    cnt[t] = 0;
    __syncthreads();
    for (int e = start + t; e < end; e += 512) {
        int2 pr = pairs[e];
        int li = pr.y & 511;
        int p = atomicAdd(&cnt[li], 1);
        csr_src[offl[li] + p] = pr.x;
    }
}

// ---------------- convert x -> rsd-prescaled bf16 (packed rows, 128 B) ----------------
__global__ __launch_bounds__(256) void cvt_k(const float* __restrict__ x, const float* __restrict__ rsd,
                                             unsigned short* __restrict__ xb) {
    int i = blockIdx.x * 256 + threadIdx.x;     // one float4 / uint2 quad
    if (i < N_NODES * 16) {
        int node = i >> 4;
        float rn = rsd[node];
        float4 v = ((const float4*)x)[i];
        unsigned int lo = ((unsigned int)f2bf(rn * v.y) << 16) | f2bf(rn * v.x);
        unsigned int hi = ((unsigned int)f2bf(rn * v.w) << 16) | f2bf(rn * v.z);
        ((uint2*)xb)[i] = make_uint2(lo, hi);
    }
}

// ---------------- per-layer: weighted neighbor sum (bf16 gather, MLP-optimized) ----
// wave per node; lane = (edge-slot g 0..7, feature-oct q 0..7), 16 B/lane.
// Per 64-edge window: ONE coalesced csr load (lane l -> edge l), indices
// distributed via __shfl; 4 independent row-gathers in flight per iteration.
__global__ __launch_bounds__(256) void agg_k(const unsigned short* __restrict__ xb,
                                             const float* __restrict__ rsd,
                                             const int* __restrict__ offs, const int* __restrict__ degi,
                                             const int* __restrict__ csr_src, float* __restrict__ s) {
    int node = blockIdx.x * 4 + (threadIdx.x >> 6);
    if (node >= N_NODES) return;
    int lane = threadIdx.x & 63;
    int g = lane >> 3;
    int q = lane & 7;
    int start = offs[node];
    int deg = degi[node];
    const uint4* in4 = (const uint4*)xb;        // row = 8 uint4
    float acc0 = 0.f, acc1 = 0.f, acc2 = 0.f, acc3 = 0.f;
    float acc4 = 0.f, acc5 = 0.f, acc6 = 0.f, acc7 = 0.f;
    for (int base = 0; base < deg; base += 64) {
        int m = min(deg - base, 64);                     // edges in this window
        int idxv = csr_src[start + base + min(lane, m - 1)];  // coalesced preload
        for (int j = 0; j < m; j += 32) {
            int e0 = j + g, e1 = j + 8 + g, e2 = j + 16 + g, e3 = j + 24 + g;
            bool v0 = e0 < m, v1 = e1 < m, v2 = e2 < m, v3 = e3 < m;
            int s0 = __shfl(idxv, e0, 64);
            int s1 = __shfl(idxv, v1 ? e1 : 0, 64);
            int s2 = __shfl(idxv, v2 ? e2 : 0, 64);
            int s3 = __shfl(idxv, v3 ? e3 : 0, 64);
            // 4 independent gathers in flight
            uint4 p0 = in4[(size_t)s0 * 8 + q];
            uint4 p1 = in4[(size_t)s1 * 8 + q];
            uint4 p2 = in4[(size_t)s2 * 8 + q];
            uint4 p3 = in4[(size_t)s3 * 8 + q];
            float w0 = v0 ? 1.f : 0.f, w1 = v1 ? 1.f : 0.f;
            float w2 = v2 ? 1.f : 0.f, w3 = v3 ? 1.f : 0.f;
            acc0 += w0 * bflo(p0.x); acc1 += w0 * bfhi(p0.x);
            acc2 += w0 * bflo(p0.y); acc3 += w0 * bfhi(p0.y);
            acc4 += w0 * bflo(p0.z); acc5 += w0 * bfhi(p0.z);
            acc6 += w0 * bflo(p0.w); acc7 += w0 * bfhi(p0.w);
            acc0 += w1 * bflo(p1.x); acc1 += w1 * bfhi(p1.x);
            acc2 += w1 * bflo(p1.y); acc3 += w1 * bfhi(p1.y);
            acc4 += w1 * bflo(p1.z); acc5 += w1 * bfhi(p1.z);
            acc6 += w1 * bflo(p1.w); acc7 += w1 * bfhi(p1.w);
            acc0 += w2 * bflo(p2.x); acc1 += w2 * bfhi(p2.x);
            acc2 += w2 * bflo(p2.y); acc3 += w2 * bfhi(p2.y);
            acc4 += w2 * bflo(p2.z); acc5 += w2 * bfhi(p2.z);
            acc6 += w2 * bflo(p2.w); acc7 += w2 * bfhi(p2.w);
            acc0 += w3 * bflo(p3.x); acc1 += w3 * bfhi(p3.x);
            acc2 += w3 * bflo(p3.y); acc3 += w3 * bfhi(p3.y);
            acc4 += w3 * bflo(p3.z); acc5 += w3 * bfhi(p3.z);
            acc6 += w3 * bflo(p3.w); acc7 += w3 * bfhi(p3.w);
        }
    }
    #pragma unroll
    for (int off = 8; off < 64; off <<= 1) {
        acc0 += __shfl_xor(acc0, off, 64); acc1 += __shfl_xor(acc1, off, 64);
        acc2 += __shfl_xor(acc2, off, 64); acc3 += __shfl_xor(acc3, off, 64);
        acc4 += __shfl_xor(acc4, off, 64); acc5 += __shfl_xor(acc5, off, 64);
        acc6 += __shfl_xor(acc6, off, 64); acc7 += __shfl_xor(acc7, off, 64);
    }
    if (g == 0) {
        float rn = rsd[node];
        float4 r0, r1;
        r0.x = rn * acc0; r0.y = rn * acc1; r0.z = rn * acc2; r0.w = rn * acc3;
        r1.x = rn * acc4; r1.y = rn * acc5; r1.z = rn * acc6; r1.w = rn * acc7;
        ((float4*)s)[node * 16 + q * 2]     = r0;
        ((float4*)s)[node * 16 + q * 2 + 1] = r1;
    }
}

// ---------------- per-layer: combine + GEMM (round-1 proven core) ----------------
// out[n, d] = act( (in[n]+s[n]) @ W1 + (s[n]*in[n]) @ W2 ); optional bf16 epilogue
// writes hb[n] = rsd[n]*h[n] (packed rows) for the next layer's aggregation.
__global__ __launch_bounds__(256) void comb_k(const float* __restrict__ in, int stride,
                                              const float* __restrict__ s,
                                              const float* __restrict__ W1, const float* __restrict__ W2,
                                              float* __restrict__ out, int act,
                                              unsigned short* __restrict__ hb, const float* __restrict__ rsd,
                                              int bfout) {
    __shared__ float W1s[D * D];
    __shared__ float W2s[D * D];
    __shared__ float aL[4][4][D];   // [wave][m][k]
    __shared__ float bL[4][4][D];
    int tid = threadIdx.x;
    {
        const float4* w1v = (const float4*)W1;
        const float4* w2v = (const float4*)W2;
        float4* w1s = (float4*)W1s;
        float4* w2s = (float4*)W2s;
        for (int t = tid; t < D * D / 4; t += 256) { w1s[t] = w1v[t]; w2s[t] = w2v[t]; }
    }
    int w = tid >> 6;
    int l = tid & 63;
    int m = l >> 4;
    int cb = (l & 15) * 4;
    __syncthreads();
    for (int it = 0; it < 2; ++it) {
        int n0 = blockIdx.x * 32 + it * 16 + w * 4;
        #pragma unroll
        for (int mm = 0; mm < 4; ++mm) {
            float xv = in[(size_t)(n0 + mm) * stride + l];
            float sp = s[(size_t)(n0 + mm) * D + l];
            aL[w][mm][l] = xv + sp;
            bL[w][mm][l] = sp * xv;
        }
        __syncthreads();
        float acc0 = 0.f, acc1 = 0.f, acc2 = 0.f, acc3 = 0.f;
        const float4* aV = (const float4*)&aL[w][m][0];
        const float4* bV = (const float4*)&bL[w][m][0];
        #pragma unroll
        for (int kk = 0; kk < 16; ++kk) {
            float4 a4 = aV[kk];
            float4 b4 = bV[kk];
            #pragma unroll
            for (int j = 0; j < 4; ++j) {
                int k = kk * 4 + j;
                float aj = (j == 0) ? a4.x : (j == 1) ? a4.y : (j == 2) ? a4.z : a4.w;
                float bj = (j == 0) ? b4.x : (j == 1) ? b4.y : (j == 2) ? b4.z : b4.w;
                float4 w1 = *(const float4*)&W1s[k * D + cb];
                float4 w2 = *(const float4*)&W2s[k * D + cb];
                acc0 += aj * w1.x + bj * w2.x;
                acc1 += aj * w1.y + bj * w2.y;
                acc2 += aj * w1.z + bj * w2.z;
                acc3 += aj * w1.w + bj * w2.w;
            }
        }
        int n = n0 + m;
        float4 r;
        r.x = acc0; r.y = acc1; r.z = acc2; r.w = acc3;
        if (act) {
            r.x = r.x >= 0.f ? r.x : NEG_SLOPE * r.x;
            r.y = r.y >= 0.f ? r.y : NEG_SLOPE * r.y;
            r.z = r.z >= 0.f ? r.z : NEG_SLOPE * r.z;
            r.w = r.w >= 0.f ? r.w : NEG_SLOPE * r.w;
        }
        *(float4*)&out[(size_t)n * 192 + cb] = r;
        if (bfout) {
            float rn = rsd[n];
            unsigned int lo = ((unsigned int)f2bf(rn * r.y) << 16) | f2bf(rn * r.x);
            unsigned int hi = ((unsigned int)f2bf(rn * r.w) << 16) | f2bf(rn * r.z);
            *(uint2*)&hb[(size_t)n * D + cb] = make_uint2(lo, hi);
        }
        __syncthreads();
    }
}

extern "C" void kernel_launch(void* const* d_in, const int* in_sizes, int n_in,
                              void* d_out, int out_size, void* d_ws, size_t ws_size,
                              hipStream_t stream) {
    const float* x   = (const float*)d_in[0];
    const float* W1a = (const float*)d_in[1];
    const float* W2a = (const float*)d_in[2];
    const float* W1b = (const float*)d_in[3];
    const float* W2b = (const float*)d_in[4];
    const int*   src = (const int*)d_in[5];
    const int*   dst = (const int*)d_in[6];
    float* out = (float*)d_out;

    // workspace layout (~65 MB); xb/hb ALIAS pairs (pairs is dead after fine_k)
    int*   btot    = (int*)d_ws;                    // NB pad 256
    int*   bcnt2   = btot + 256;                    // NB pad 256
    int*   bbase   = bcnt2 + 256;                   // NB+1 pad 256
    int*   degi    = bbase + 256;                   // N
    int*   offs    = degi + N_NODES;                // N
    float* rsd     = (float*)(offs + N_NODES);      // N
    int*   csr_src = (int*)(rsd + N_NODES);         // E
    int2*  pairs   = (int2*)(csr_src + N_EDGES);    // E (25.6 MB)
    unsigned short* xb = (unsigned short*)pairs;        // N*64 bf16 (12.8 MB)
    unsigned short* hb = xb + (size_t)N_NODES * D;      // N*64 bf16 (12.8 MB)
    float* s       = (float*)(pairs + N_EDGES);     // N*D

    hipMemsetAsync(btot, 0, 512 * sizeof(int), stream);  // btot + bcnt2

    bhist_k<<<NBIN, 256, 0, stream>>>(dst, btot);
    bscan_k<<<1, 256, 0, stream>>>(btot, bbase);
    bucket_k<<<NBIN, 256, 0, stream>>>(src, dst, bbase, bcnt2, pairs);
    fine_k<<<NB, 512, 0, stream>>>(pairs, bbase, degi, offs, rsd, csr_src);
    cvt_k<<<(N_NODES * 16 + 255) / 256, 256, 0, stream>>>(x, rsd, xb);   // pairs dead, rsd ready

    int ab = (N_NODES + 3) / 4;   // wave per node
    int cbg = N_NODES / 32;       // 3125, exact

    // layer 1: h1 = lrelu(conv(x, W1a, W2a)) -> out cols [0,64), hb = rsd*h1 (bf16)
    agg_k<<<ab, 256, 0, stream>>>(xb, rsd, offs, degi, csr_src, s);
    comb_k<<<cbg, 256, 0, stream>>>(x, D, s, W1a, W2a, out + 0, 1, hb, rsd, 1);
    // layer 2: h2 = lrelu(conv(h1, W1b, W2b)) -> out cols [64,128), hb = rsd*h2 (bf16)
    agg_k<<<ab, 256, 0, stream>>>(hb, rsd, offs, degi, csr_src, s);
    comb_k<<<cbg, 256, 0, stream>>>(out + 0, 192, s, W1b, W2b, out + 64, 1, hb, rsd, 1);
    // layer 3: h3 = conv(h2, W1b, W2b) (no act) -> out cols [128,192)
    agg_k<<<ab, 256, 0, stream>>>(hb, rsd, offs, degi, csr_src, s);
    comb_k<<<cbg, 256, 0, stream>>>(out + 64, 192, s, W1b, W2b, out + 128, 0, hb, rsd, 0);
}

// Round 5
// 461.253 us; speedup vs baseline: 1.8687x; 1.1579x over previous
//
#include <hip/hip_runtime.h>
#include <hip/hip_bf16.h>

#define N_NODES 100000
#define N_EDGES 3200000
#define D 64
#define NEG_SLOPE 0.01f

#define B_SHIFT 9                          // bucket = 512 nodes
#define NB ((N_NODES + 511) >> B_SHIFT)    // 196 buckets
#define T_EDGES 4096                       // edges per binning block
#define NBIN ((N_EDGES + T_EDGES - 1) / T_EDGES)  // 782 binning blocks

using bf16x8 = __attribute__((ext_vector_type(8))) short;   // MFMA A/B frag (4 VGPR)
using f32x4  = __attribute__((ext_vector_type(4))) float;   // MFMA C/D frag

__device__ __forceinline__ unsigned short f2bf(float f) {
    __hip_bfloat16 h = __float2bfloat16(f);
    return *reinterpret_cast<unsigned short*>(&h);
}
__device__ __forceinline__ float bflo(unsigned int u) { return __uint_as_float(u << 16); }
__device__ __forceinline__ float bfhi(unsigned int u) { return __uint_as_float(u & 0xffff0000u); }
__device__ __forceinline__ float bf2f(unsigned short h) { return __uint_as_float(((unsigned int)h) << 16); }

// ---------------- bucket histogram (196 counters, LDS-accumulated) ----------------
__global__ __launch_bounds__(256) void bhist_k(const int* __restrict__ dst, int* __restrict__ btot) {
    __shared__ int hist[NB];
    int tid = threadIdx.x;
    for (int b = tid; b < NB; b += 256) hist[b] = 0;
    __syncthreads();
    int e0 = blockIdx.x * T_EDGES;
    int e1 = min(e0 + T_EDGES, N_EDGES);
    for (int e = e0 + tid; e < e1; e += 256) atomicAdd(&hist[dst[e] >> B_SHIFT], 1);
    __syncthreads();
    for (int b = tid; b < NB; b += 256) {
        int h = hist[b];
        if (h) atomicAdd(&btot[b], h);
    }
}

// one-block exclusive scan over the 196 bucket totals -> bbase[0..NB]
__global__ __launch_bounds__(256) void bscan_k(const int* __restrict__ btot, int* __restrict__ bbase) {
    __shared__ int wsum[4];
    int t = threadIdx.x;
    int lane = t & 63, w = t >> 6;
    int v = (t < NB) ? btot[t] : 0;
    int incl = v;
    #pragma unroll
    for (int o = 1; o < 64; o <<= 1) {
        int u = __shfl_up(incl, o, 64);
        if (lane >= o) incl += u;
    }
    if (lane == 63) wsum[w] = incl;
    __syncthreads();
    int woff = 0;
    for (int k = 0; k < w; ++k) woff += wsum[k];
    if (t < NB) bbase[t] = woff + incl - v;
    if (t == NB) bbase[NB] = N_EDGES;
}

// ---------------- coarse placement: LDS-reorder then coalesced stream-out ----------------
__global__ __launch_bounds__(256) void bucket_k(const int* __restrict__ src, const int* __restrict__ dst,
                                                const int* __restrict__ bbase, int* __restrict__ bcnt2,
                                                int2* __restrict__ pairs) {
    __shared__ int hist[NB];
    __shared__ int lbase[NB];
    __shared__ int lcnt[NB];
    __shared__ int gbase[NB];   // global run base with -lbase folded in
    __shared__ int wsum[4];
    __shared__ int2 buf[T_EDGES];   // 32 KB reorder buffer
    int tid = threadIdx.x;
    for (int b = tid; b < NB; b += 256) { hist[b] = 0; lcnt[b] = 0; }
    __syncthreads();
    int e0 = blockIdx.x * T_EDGES;
    int e1 = min(e0 + T_EDGES, N_EDGES);
    for (int e = e0 + tid; e < e1; e += 256) atomicAdd(&hist[dst[e] >> B_SHIFT], 1);
    __syncthreads();
    {
        int v = (tid < NB) ? hist[tid] : 0;
        int lane = tid & 63, w = tid >> 6;
        int incl = v;
        #pragma unroll
        for (int o = 1; o < 64; o <<= 1) {
            int u = __shfl_up(incl, o, 64);
            if (lane >= o) incl += u;
        }
        if (lane == 63) wsum[w] = incl;
        __syncthreads();
        int woff = 0;
        for (int k = 0; k < w; ++k) woff += wsum[k];
        if (tid < NB) {
            int excl = woff + incl - v;
            lbase[tid] = excl;
            int p = v ? atomicAdd(&bcnt2[tid], v) : 0;
            gbase[tid] = bbase[tid] + p - excl;   // so stream-out addr = gbase[b] + i
        }
    }
    __syncthreads();
    for (int e = e0 + tid; e < e1; e += 256) {
        int sv = src[e], dv = dst[e];
        int b = dv >> B_SHIFT;
        int loc = lbase[b] + atomicAdd(&lcnt[b], 1);
        buf[loc] = make_int2(sv, dv);
    }
    __syncthreads();
    int n = e1 - e0;
    for (int i = tid; i < n; i += 256) {
        int2 pr = buf[i];
        int b = pr.y >> B_SHIFT;
        pairs[gbase[b] + i] = pr;
    }
}

// ---------------- fine: per-bucket degree count + scan + scatter ----------------
__global__ __launch_bounds__(512) void fine_k(const int2* __restrict__ pairs, const int* __restrict__ bbase,
                                              int* __restrict__ degi, int* __restrict__ offs,
                                              float* __restrict__ rsd, int* __restrict__ csr_src) {
    __shared__ int cnt[512];
    __shared__ int offl[512];
    __shared__ int wsum[8];
    int b = blockIdx.x, t = threadIdx.x;
    int start = bbase[b];
    int end = bbase[b + 1];
    cnt[t] = 0;
    __syncthreads();
    for (int e = start + t; e < end; e += 512) atomicAdd(&cnt[pairs[e].y & 511], 1);
    __syncthreads();
    int d = cnt[t];
    int lane = t & 63, w = t >> 6;
    int incl = d;
    #pragma unroll
    for (int o = 1; o < 64; o <<= 1) {
        int u = __shfl_up(incl, o, 64);
        if (lane >= o) incl += u;
    }
    if (lane == 63) wsum[w] = incl;
    __syncthreads();
    int woff = 0;
    for (int k = 0; k < w; ++k) woff += wsum[k];
    int myoff = start + woff + incl - d;
    offl[t] = myoff;
    int n = (b << B_SHIFT) + t;
    if (n < N_NODES) {
        degi[n] = d;
        offs[n] = myoff;
        rsd[n] = rsqrtf((float)(d > 0 ? d : 1));
    }
    cnt[t] = 0;
    __syncthreads();
    for (int e = start + t; e < end; e += 512) {
        int2 pr = pairs[e];
        int li = pr.y & 511;
        int p = atomicAdd(&cnt[li], 1);
        csr_src[offl[li] + p] = pr.x;
    }
}

// ---------------- convert x -> rsd-prescaled bf16 (packed rows, 128 B) ----------------
__global__ __launch_bounds__(256) void cvt_k(const float* __restrict__ x, const float* __restrict__ rsd,
                                             unsigned short* __restrict__ xb) {
    int i = blockIdx.x * 256 + threadIdx.x;     // one float4 / uint2 quad
    if (i < N_NODES * 16) {
        int node = i >> 4;
        float rn = rsd[node];
        float4 v = ((const float4*)x)[i];
        unsigned int lo = ((unsigned int)f2bf(rn * v.y) << 16) | f2bf(rn * v.x);
        unsigned int hi = ((unsigned int)f2bf(rn * v.w) << 16) | f2bf(rn * v.z);
        ((uint2*)xb)[i] = make_uint2(lo, hi);
    }
}

// ---------------- per-layer: weighted neighbor sum (bf16 gather, MLP-optimized) ----
// wave per node; lane = (edge-slot g 0..7, feature-oct q 0..7), 16 B/lane.
// Per 64-edge window: ONE coalesced csr load (lane l -> edge l), indices
// distributed via __shfl; 4 independent row-gathers in flight per iteration.
__global__ __launch_bounds__(256) void agg_k(const unsigned short* __restrict__ xb,
                                             const float* __restrict__ rsd,
                                             const int* __restrict__ offs, const int* __restrict__ degi,
                                             const int* __restrict__ csr_src, float* __restrict__ s) {
    int node = blockIdx.x * 4 + (threadIdx.x >> 6);
    if (node >= N_NODES) return;
    int lane = threadIdx.x & 63;
    int g = lane >> 3;
    int q = lane & 7;
    int start = offs[node];
    int deg = degi[node];
    const uint4* in4 = (const uint4*)xb;        // row = 8 uint4
    float acc0 = 0.f, acc1 = 0.f, acc2 = 0.f, acc3 = 0.f;
    float acc4 = 0.f, acc5 = 0.f, acc6 = 0.f, acc7 = 0.f;
    for (int base = 0; base < deg; base += 64) {
        int m = min(deg - base, 64);                     // edges in this window
        int idxv = csr_src[start + base + min(lane, m - 1)];  // coalesced preload
        for (int j = 0; j < m; j += 32) {
            int e0 = j + g, e1 = j + 8 + g, e2 = j + 16 + g, e3 = j + 24 + g;
            bool v0 = e0 < m, v1 = e1 < m, v2 = e2 < m, v3 = e3 < m;
            int s0 = __shfl(idxv, e0, 64);
            int s1 = __shfl(idxv, v1 ? e1 : 0, 64);
            int s2 = __shfl(idxv, v2 ? e2 : 0, 64);
            int s3 = __shfl(idxv, v3 ? e3 : 0, 64);
            // 4 independent gathers in flight
            uint4 p0 = in4[(size_t)s0 * 8 + q];
            uint4 p1 = in4[(size_t)s1 * 8 + q];
            uint4 p2 = in4[(size_t)s2 * 8 + q];
            uint4 p3 = in4[(size_t)s3 * 8 + q];
            float w0 = v0 ? 1.f : 0.f, w1 = v1 ? 1.f : 0.f;
            float w2 = v2 ? 1.f : 0.f, w3 = v3 ? 1.f : 0.f;
            acc0 += w0 * bflo(p0.x); acc1 += w0 * bfhi(p0.x);
            acc2 += w0 * bflo(p0.y); acc3 += w0 * bfhi(p0.y);
            acc4 += w0 * bflo(p0.z); acc5 += w0 * bfhi(p0.z);
            acc6 += w0 * bflo(p0.w); acc7 += w0 * bfhi(p0.w);
            acc0 += w1 * bflo(p1.x); acc1 += w1 * bfhi(p1.x);
            acc2 += w1 * bflo(p1.y); acc3 += w1 * bfhi(p1.y);
            acc4 += w1 * bflo(p1.z); acc5 += w1 * bfhi(p1.z);
            acc6 += w1 * bflo(p1.w); acc7 += w1 * bfhi(p1.w);
            acc0 += w2 * bflo(p2.x); acc1 += w2 * bfhi(p2.x);
            acc2 += w2 * bflo(p2.y); acc3 += w2 * bfhi(p2.y);
            acc4 += w2 * bflo(p2.z); acc5 += w2 * bfhi(p2.z);
            acc6 += w2 * bflo(p2.w); acc7 += w2 * bfhi(p2.w);
            acc0 += w3 * bflo(p3.x); acc1 += w3 * bfhi(p3.x);
            acc2 += w3 * bflo(p3.y); acc3 += w3 * bfhi(p3.y);
            acc4 += w3 * bflo(p3.z); acc5 += w3 * bfhi(p3.z);
            acc6 += w3 * bflo(p3.w); acc7 += w3 * bfhi(p3.w);
        }
    }
    #pragma unroll
    for (int off = 8; off < 64; off <<= 1) {
        acc0 += __shfl_xor(acc0, off, 64); acc1 += __shfl_xor(acc1, off, 64);
        acc2 += __shfl_xor(acc2, off, 64); acc3 += __shfl_xor(acc3, off, 64);
        acc4 += __shfl_xor(acc4, off, 64); acc5 += __shfl_xor(acc5, off, 64);
        acc6 += __shfl_xor(acc6, off, 64); acc7 += __shfl_xor(acc7, off, 64);
    }
    if (g == 0) {
        float rn = rsd[node];
        float4 r0, r1;
        r0.x = rn * acc0; r0.y = rn * acc1; r0.z = rn * acc2; r0.w = rn * acc3;
        r1.x = rn * acc4; r1.y = rn * acc5; r1.z = rn * acc6; r1.w = rn * acc7;
        ((float4*)s)[node * 16 + q * 2]     = r0;
        ((float4*)s)[node * 16 + q * 2 + 1] = r1;
    }
}

// ---------------- per-layer: combine + GEMM on MFMA (split-precision bf16) --------
// out[n,:] = act( (in+s) @ W1 + (s*in) @ W2 ), computed as 3-term bf16 split:
// a@W ~= ah@Wh + al@Wh + ah@Wl  (residual ~2^-17 relative; f32-equivalent).
// Block = 32 rows; wave w owns cols [16w,16w+16). No LDS, no barriers.
// MFMA v_mfma_f32_16x16x32_bf16 layouts:
//   A: lane l holds A[l&15][(l>>4)*8 + i]       (row-side: our a/b rows)
//   B: lane l holds B[(l>>4)*8 + i][l&15]       (col-side: W)
//   D: lane l holds D[(l>>4)*4 + r][l&15]       (m89-verified)
__global__ __launch_bounds__(256) void comb_k(const float* __restrict__ in, int stride,
                                              const float* __restrict__ s,
                                              const float* __restrict__ W1, const float* __restrict__ W2,
                                              float* __restrict__ out, int act,
                                              unsigned short* __restrict__ hb, const float* __restrict__ rsd,
                                              int bfout) {
    int tid = threadIdx.x;
    int w = tid >> 6;          // wave = column-tile index
    int l = tid & 63;
    int lr = l & 15;           // A-row / B-col / D-col
    int lk = l >> 4;           // k-group (8 consecutive k per group)

    // ---- W fragments, hi/lo split (once per block; W is L2-hot) ----
    bf16x8 w1h[2], w1l[2], w2h[2], w2l[2];     // [kstep]
    #pragma unroll
    for (int s2 = 0; s2 < 2; ++s2) {
        #pragma unroll
        for (int i = 0; i < 8; ++i) {
            int k = s2 * 32 + lk * 8 + i;
            float v1 = W1[k * D + w * 16 + lr];
            float v2 = W2[k * D + w * 16 + lr];
            unsigned short h1 = f2bf(v1);
            unsigned short h2 = f2bf(v2);
            w1h[s2][i] = (short)h1; w1l[s2][i] = (short)f2bf(v1 - bf2f(h1));
            w2h[s2][i] = (short)h2; w2l[s2][i] = (short)f2bf(v2 - bf2f(h2));
        }
    }

    int n0 = blockIdx.x * 32;
    // ---- A fragments for 2 row-tiles: a = in+s (hi/lo), b = s*in (hi/lo) ----
    bf16x8 ah[2][2], al[2][2], bh[2][2], bl[2][2];   // [rowtile][kstep]
    #pragma unroll
    for (int rt = 0; rt < 2; ++rt) {
        int n = n0 + rt * 16 + lr;
        const float* ip = in + (size_t)n * stride + lk * 8;
        const float* sp = s + (size_t)n * D + lk * 8;
        #pragma unroll
        for (int s2 = 0; s2 < 2; ++s2) {
            float ia[8], sa[8];
            *(float4*)&ia[0] = *(const float4*)(ip + s2 * 32);
            *(float4*)&ia[4] = *(const float4*)(ip + s2 * 32 + 4);
            *(float4*)&sa[0] = *(const float4*)(sp + s2 * 32);
            *(float4*)&sa[4] = *(const float4*)(sp + s2 * 32 + 4);
            #pragma unroll
            for (int i = 0; i < 8; ++i) {
                float a = ia[i] + sa[i];
                float b = sa[i] * ia[i];
                unsigned short hA = f2bf(a);
                unsigned short hB = f2bf(b);
                ah[rt][s2][i] = (short)hA; al[rt][s2][i] = (short)f2bf(a - bf2f(hA));
                bh[rt][s2][i] = (short)hB; bl[rt][s2][i] = (short)f2bf(b - bf2f(hB));
            }
        }
    }

    // ---- MFMA accumulation ----
    f32x4 acc[2] = {{0.f, 0.f, 0.f, 0.f}, {0.f, 0.f, 0.f, 0.f}};
    #pragma unroll
    for (int rt = 0; rt < 2; ++rt) {
        #pragma unroll
        for (int s2 = 0; s2 < 2; ++s2) {
            acc[rt] = __builtin_amdgcn_mfma_f32_16x16x32_bf16(ah[rt][s2], w1h[s2], acc[rt], 0, 0, 0);
            acc[rt] = __builtin_amdgcn_mfma_f32_16x16x32_bf16(al[rt][s2], w1h[s2], acc[rt], 0, 0, 0);
            acc[rt] = __builtin_amdgcn_mfma_f32_16x16x32_bf16(ah[rt][s2], w1l[s2], acc[rt], 0, 0, 0);
            acc[rt] = __builtin_amdgcn_mfma_f32_16x16x32_bf16(bh[rt][s2], w2h[s2], acc[rt], 0, 0, 0);
            acc[rt] = __builtin_amdgcn_mfma_f32_16x16x32_bf16(bl[rt][s2], w2h[s2], acc[rt], 0, 0, 0);
            acc[rt] = __builtin_amdgcn_mfma_f32_16x16x32_bf16(bh[rt][s2], w2l[s2], acc[rt], 0, 0, 0);
        }
    }

    // ---- epilogue: activation, f32 out, optional bf16 next-layer rows ----
    #pragma unroll
    for (int rt = 0; rt < 2; ++rt) {
        #pragma unroll
        for (int r = 0; r < 4; ++r) {
            int n = n0 + rt * 16 + lk * 4 + r;
            float v = acc[rt][r];
            if (act) v = v >= 0.f ? v : NEG_SLOPE * v;
            out[(size_t)n * 192 + w * 16 + lr] = v;
            if (bfout) hb[(size_t)n * D + w * 16 + lr] = f2bf(rsd[n] * v);
        }
    }
}

extern "C" void kernel_launch(void* const* d_in, const int* in_sizes, int n_in,
                              void* d_out, int out_size, void* d_ws, size_t ws_size,
                              hipStream_t stream) {
    const float* x   = (const float*)d_in[0];
    const float* W1a = (const float*)d_in[1];
    const float* W2a = (const float*)d_in[2];
    const float* W1b = (const float*)d_in[3];
    const float* W2b = (const float*)d_in[4];
    const int*   src = (const int*)d_in[5];
    const int*   dst = (const int*)d_in[6];
    float* out = (float*)d_out;

    // workspace layout (~65 MB); xb/hb ALIAS pairs (pairs is dead after fine_k)
    int*   btot    = (int*)d_ws;                    // NB pad 256
    int*   bcnt2   = btot + 256;                    // NB pad 256
    int*   bbase   = bcnt2 + 256;                   // NB+1 pad 256
    int*   degi    = bbase + 256;                   // N
    int*   offs    = degi + N_NODES;                // N
    float* rsd     = (float*)(offs + N_NODES);      // N
    int*   csr_src = (int*)(rsd + N_NODES);         // E
    int2*  pairs   = (int2*)(csr_src + N_EDGES);    // E (25.6 MB)
    unsigned short* xb = (unsigned short*)pairs;        // N*64 bf16 (12.8 MB)
    unsigned short* hb = xb + (size_t)N_NODES * D;      // N*64 bf16 (12.8 MB)
    float* s       = (float*)(pairs + N_EDGES);     // N*D

    hipMemsetAsync(btot, 0, 512 * sizeof(int), stream);  // btot + bcnt2

    bhist_k<<<NBIN, 256, 0, stream>>>(dst, btot);
    bscan_k<<<1, 256, 0, stream>>>(btot, bbase);
    bucket_k<<<NBIN, 256, 0, stream>>>(src, dst, bbase, bcnt2, pairs);
    fine_k<<<NB, 512, 0, stream>>>(pairs, bbase, degi, offs, rsd, csr_src);
    cvt_k<<<(N_NODES * 16 + 255) / 256, 256, 0, stream>>>(x, rsd, xb);   // pairs dead, rsd ready

    int ab = (N_NODES + 3) / 4;   // wave per node
    int cbg = N_NODES / 32;       // 3125, exact

    // layer 1: h1 = lrelu(conv(x, W1a, W2a)) -> out cols [0,64), hb = rsd*h1 (bf16)
    agg_k<<<ab, 256, 0, stream>>>(xb, rsd, offs, degi, csr_src, s);
    comb_k<<<cbg, 256, 0, stream>>>(x, D, s, W1a, W2a, out + 0, 1, hb, rsd, 1);
    // layer 2: h2 = lrelu(conv(h1, W1b, W2b)) -> out cols [64,128), hb = rsd*h2 (bf16)
    agg_k<<<ab, 256, 0, stream>>>(hb, rsd, offs, degi, csr_src, s);
    comb_k<<<cbg, 256, 0, stream>>>(out + 0, 192, s, W1b, W2b, out + 64, 1, hb, rsd, 1);
    // layer 3: h3 = conv(h2, W1b, W2b) (no act) -> out cols [128,192)
    agg_k<<<ab, 256, 0, stream>>>(hb, rsd, offs, degi, csr_src, s);
    comb_k<<<cbg, 256, 0, stream>>>(out + 64, 192, s, W1b, W2b, out + 128, 0, hb, rsd, 0);
}